// Round 6
// baseline (289.639 us; speedup 1.0000x reference)
//
#include <hip/hip_runtime.h>

#define NN 256     // Preisach mesh size
#define TT 16      // outputs per block
#define CH 8192    // 32 KB LDS staging chunk (floats)

__device__ __forceinline__ float softplus_f(float x) {
    if (x > 20.0f) return x;
    return log1pf(expf(x));
}

// Single self-sufficient kernel. Block b handles outputs [b*TT, b*TT+TT).
// Carry-in state via scatter+scan over step records; dens prefix recomputed
// per block from raw via LDS-staged serial row scans.
__global__ void __launch_bounds__(256)
k_one(const float* __restrict__ h_g, const float* __restrict__ raw,
      float* __restrict__ out, int M)
{
    __shared__ float xs[NN];
    __shared__ float buf[CH];
    __shared__ float pkb[TT + 1][NN];
    __shared__ int   Lup[NN + 1], Ldn[NN + 1];
    __shared__ int   rec_s[TT + 1];
    __shared__ int   sst[TT + 1], skidx[TT + 1];
    __shared__ float red[4 * (TT + 2)];
    __shared__ float tot[TT + 2];

    int b = blockIdx.x, tid = threadIdx.x;
    int t0 = b * TT;
    int Tb = min(TT, M - t0);

    xs[tid] = (float)((double)tid / 255.0);   // np.linspace(0,1,256) f64->f32
    Lup[tid] = 0; Ldn[tid] = 0;
    if (tid == 0) { Lup[NN] = 0; Ldn[NN] = 0; }
    __syncthreads();

    // tau = 0: hs[0]=1.0, prev = hs[M] (roll wrap). Up-step iff hs[M] < 1.
    if (tid == 0) {
        float hsM = (h_g[M - 1] + 1.0f) * 0.5f;
        if (hsM < 1.0f) Lup[255] = 1;          // e = tau+1 = 1; ih = 255
    }

    // carry steps tau = 1..t0: scatter last-flip step into per-bin max tables.
    // Ue_i = max{e : up-step, ih > i}  -> suffix-max of Lup
    // De_j = max{e : down-step, jh <= j} -> prefix-max of Ldn
    for (int tau = tid + 1; tau <= t0; tau += 256) {
        float cur  = (h_g[tau - 1] + 1.0f) * 0.5f;
        float prev = (tau == 1) ? 1.0f : (h_g[tau - 2] + 1.0f) * 0.5f;
        if (cur != prev) {
            int v = min(max((int)(cur * 255.0f), 0), 255);   // ih = #{x < cur}
            while (v > 0 && xs[v - 1] >= cur) --v;
            while (v < 255 && xs[v] < cur) ++v;
            if (cur > prev) {
                atomicMax(&Lup[v], tau + 1);
            } else {
                int v2 = v;                                   // jh = #{x <= cur}
                while (v2 < 256 && xs[v2] <= cur) ++v2;
                atomicMax(&Ldn[v2], tau + 1);
            }
        }
    }

    // walk-step records for this block's TT steps
    if (tid < TT) {
        int rec = 0;
        if (tid < Tb) {
            int tau = t0 + 1 + tid;
            float cur  = (h_g[tau - 1] + 1.0f) * 0.5f;
            float prev = (tau == 1) ? 1.0f : (h_g[tau - 2] + 1.0f) * 0.5f;
            int d = (cur > prev) ? 2 : ((cur < prev) ? 0 : 1);
            int v = min(max((int)(cur * 255.0f), 0), 255);
            while (v > 0 && xs[v - 1] >= cur) --v;
            while (v < 255 && xs[v] < cur) ++v;
            int v2 = v;
            while (v2 < 256 && xs[v2] <= cur) ++v2;
            rec = d | (v << 2) | (v2 << 11);
        }
        rec_s[1 + tid] = rec;
    }
    __syncthreads();

    // stable rank-sort the TT stop positions (jh per walk step), ascending
    if (tid < TT) {
        int k = 1 + tid;
        int jk = (rec_s[k] >> 11) & 0x1FF;
        int rank = 0;
        for (int m = 1; m <= TT; ++m) {
            int jm = (rec_s[m] >> 11) & 0x1FF;
            if (jm < jk || (jm == jk && m < k)) ++rank;
        }
        sst[1 + rank] = jk;
        skidx[1 + rank] = k;
    }

    // in-place Hillis-Steele: prefix-max over Ldn, suffix-max over Lup
    for (int off = 1; off < NN; off <<= 1) {
        int a = (tid >= off) ? Ldn[tid - off] : 0;
        int s = (tid + off < NN) ? Lup[tid + off] : 0;
        __syncthreads();
        if (a > Ldn[tid]) Ldn[tid] = a;
        if (s > Lup[tid]) Lup[tid] = s;
        __syncthreads();
    }
    int Ue = (tid < NN - 1) ? Lup[tid + 1] : 0;   // exclusive suffix from tid+1
    // c = #{j : De_j < Ue}; Ldn (post-scan) is non-decreasing
    int lo = 0, hi = NN;
    while (lo < hi) { int m = (lo + hi) >> 1; if (Ldn[m] < Ue) lo = m + 1; else hi = m; }
    int c = min(lo, tid + 1);

    // dens row prefix: stage softplus(raw) triangle in 32 KB chunks,
    // thread tid serially scans its row, capturing prefix at c and at stops.
    const int tri = NN * (NN + 1) / 2;
    int base = tid * (tid + 1) / 2;
    float acc = 0.0f, wc = 0.0f;
    int j = 0, p = 1;
    for (int q0 = 0; q0 < tri; q0 += CH) {
        int qn = min(CH, tri - q0);
        __syncthreads();                        // buf reuse
        for (int u = tid; u < qn; u += 256)
            buf[u] = softplus_f(raw[q0 + u]);
        __syncthreads();
        int lend = q0 + qn;
        while (j <= tid && base + j < lend) {
            float dv = buf[base + j - q0];
            while (p <= TT && sst[p] == j) { pkb[skidx[p]][tid] = acc; ++p; }
            if (j == c) wc = acc;               // Pref[tid][c] (exclusive)
            acc += dv;
            ++j;
        }
    }
    float RT = acc;                              // row total
    float ww = (c <= tid) ? (2.0f * wc - RT) : RT;

    // barrier-free walk: per-thread delta per step
    float vals[TT + 2];
    vals[0] = RT; vals[1] = ww;
    int cc = c;
    #pragma unroll
    for (int k = 1; k <= TT; ++k) {
        float dl = 0.0f;
        if (k <= Tb) {
            int rec = rec_s[k];
            int d = rec & 3;
            if (d == 2) {                        // up: rows i < ih -> +RowTot
                int ih = (rec >> 2) & 0x1FF;
                if (tid < ih) { dl = RT - ww; ww = RT; cc = tid + 1; }
            } else if (d == 0) {                 // down: truncate prefix to jh
                int jh = (rec >> 11) & 0x1FF;
                if (cc > jh) { float wn = 2.0f * pkb[k][tid] - RT; dl = wn - ww; ww = wn; cc = jh; }
            }
        }
        vals[1 + k] = dl;
    }

    // reduce all TT+2 quantities: wave shuffle then cross-wave via LDS
    #pragma unroll
    for (int q = 0; q < TT + 2; ++q)
        for (int off = 32; off; off >>= 1)
            vals[q] += __shfl_down(vals[q], off, 64);
    int lane = tid & 63, wv = tid >> 6;
    if (lane == 0) {
        #pragma unroll
        for (int q = 0; q < TT + 2; ++q) red[wv * (TT + 2) + q] = vals[q];
    }
    __syncthreads();
    if (tid < TT + 2)
        tot[tid] = red[tid] + red[(TT + 2) + tid] + red[2 * (TT + 2) + tid] + red[3 * (TT + 2) + tid];
    __syncthreads();
    if (tid < TT) {                              // prefix-scan deltas -> outputs
        float x = tot[2 + tid];
        #pragma unroll
        for (int off = 1; off < TT; off <<= 1) {
            float y = __shfl_up(x, off, 64);
            if (tid >= off) x += y;
        }
        if (tid < Tb) out[t0 + tid] = (tot[1] + x) * (1.0f / tot[0]);
    }
}

extern "C" void kernel_launch(void* const* d_in, const int* in_sizes, int n_in,
                              void* d_out, int out_size, void* d_ws, size_t ws_size,
                              hipStream_t stream) {
    const float* h   = (const float*)d_in[0];
    const float* raw = (const float*)d_in[1];
    float* out = (float*)d_out;
    int M = in_sizes[0];            // 4000
    int G = (M + TT - 1) / TT;      // 250 blocks, all co-resident

    k_one<<<G, 256, 0, stream>>>(h, raw, out, M);
}

// Round 7
// 74.026 us; speedup vs baseline: 3.9126x; 3.9126x over previous
//
#include <hip/hip_runtime.h>

#define NN 256     // Preisach mesh size
#define TT 16      // outputs per block in kB
// G = ceil(M/TT) = 250 blocks for M=4000

__device__ __forceinline__ float softplus_f(float x) {
    if (x > 20.0f) return x;
    return log1pf(expf(x));
}

// ---- kA: per-row prefix sums of dens = softplus(raw), transposed store ----
// PrefT[k*NN + i] = sum_{j<k} dens[i][j] (k = 0..256); RowTot[i] = row sum.
// Wave shuffle scan: 1 barrier instead of 16.
__global__ void __launch_bounds__(256)
kA(const float* __restrict__ raw,
   float* __restrict__ PrefT, float* __restrict__ RowTot)
{
    __shared__ float wsum[4];
    int b = blockIdx.x, j = threadIdx.x;
    float v = 0.0f;
    if (j <= b) v = softplus_f(raw[b * (b + 1) / 2 + j]);
    // inclusive scan within each 64-lane wave
    float x = v;
    #pragma unroll
    for (int off = 1; off < 64; off <<= 1) {
        float y = __shfl_up(x, off, 64);
        if ((j & 63) >= off) x += y;
    }
    int wv = j >> 6;
    if ((j & 63) == 63) wsum[wv] = x;
    __syncthreads();
    float add = 0.0f;
    #pragma unroll
    for (int w = 0; w < 4; ++w)
        if (w < wv) add += wsum[w];
    x += add;
    PrefT[(j + 1) * NN + b] = x;       // inclusive prefix -> slot j+1
    if (j == 0)      PrefT[b] = 0.0f;
    if (j == NN - 1) RowTot[b] = x;
}

// ---- kB: block b -> outputs [b*TT, b*TT+TT). Carry-in state from scatter
// over steps 0..t0 (last-flip bins + prefix/suffix max scans), then the
// barrier-free TT-step incremental walk against PrefT.
__global__ void __launch_bounds__(256)
kB(const float* __restrict__ h_g,
   const float* __restrict__ PrefT, const float* __restrict__ RowTot,
   float* __restrict__ out, int M)
{
    __shared__ float xs[NN];
    __shared__ int   Lup[NN + 1], Ldn[NN + 1];
    __shared__ int   rec_s[TT + 1];
    __shared__ float red[4 * (TT + 2)];
    __shared__ float tot[TT + 2];

    int b = blockIdx.x, tid = threadIdx.x;
    int t0 = b * TT;
    int Tb = min(TT, M - t0);

    xs[tid] = (float)((double)tid / 255.0);   // np.linspace(0,1,256) f64->f32
    Lup[tid] = 0; Ldn[tid] = 0;
    if (tid == 0) { Lup[NN] = 0; Ldn[NN] = 0; }
    __syncthreads();

    // tau = 0: hs[0] = 1.0, prev = hs[M] (roll wrap). Up-step iff hs[M] < 1.
    if (tid == 0) {
        float hsM = (h_g[M - 1] + 1.0f) * 0.5f;
        if (hsM < 1.0f) atomicMax(&Lup[255], 1);   // e = 1; ih = #{x<1} = 255
    }

    // carry steps tau = 1..t0: scatter last-flip step into per-bin max tables.
    //   up-step flips rows i < ih   -> Ue_i = suffix-max of Lup over bins >= i+1
    //   down-step flips cols j >= jh -> De_j = prefix-max of Ldn over bins <= j
    for (int tau = tid + 1; tau <= t0; tau += 256) {
        float cur  = (h_g[tau - 1] + 1.0f) * 0.5f;
        float prev = (tau == 1) ? 1.0f : (h_g[tau - 2] + 1.0f) * 0.5f;
        if (cur != prev) {
            int v = min(max((int)(cur * 255.0f), 0), 255);   // snap to ih
            while (v > 0 && xs[v - 1] >= cur) --v;
            while (v < 255 && xs[v] < cur) ++v;
            if (cur > prev) {
                atomicMax(&Lup[v], tau + 1);
            } else {
                int v2 = v;                                   // jh = #{x <= cur}
                while (v2 < 256 && xs[v2] <= cur) ++v2;
                atomicMax(&Ldn[v2], tau + 1);
            }
        }
    }

    // packed records for this block's TT walk steps
    if (tid < TT) {
        int rec = 0;
        if (tid < Tb) {
            int tau = t0 + 1 + tid;
            float cur  = (h_g[tau - 1] + 1.0f) * 0.5f;
            float prev = (tau == 1) ? 1.0f : (h_g[tau - 2] + 1.0f) * 0.5f;
            int d = (cur > prev) ? 2 : ((cur < prev) ? 0 : 1);
            int v = min(max((int)(cur * 255.0f), 0), 255);
            while (v > 0 && xs[v - 1] >= cur) --v;
            while (v < 255 && xs[v] < cur) ++v;
            int v2 = v;
            while (v2 < 256 && xs[v2] <= cur) ++v2;
            rec = d | (v << 2) | (v2 << 11);
        }
        rec_s[1 + tid] = rec;
    }
    __syncthreads();

    // in-place scans: prefix-max over Ldn, suffix-max over Lup (8 rounds)
    for (int off = 1; off < NN; off <<= 1) {
        int a = (tid >= off) ? Ldn[tid - off] : 0;
        int s = (tid + off < NN) ? Lup[tid + off] : 0;
        __syncthreads();
        if (a > Ldn[tid]) Ldn[tid] = a;
        if (s > Lup[tid]) Lup[tid] = s;
        __syncthreads();
    }
    int Ue = (tid < NN - 1) ? Lup[tid + 1] : 0;

    // prefetch PrefT rows for each walk step's jh (coalesced, L2-resident)
    float pk[TT + 1];
    #pragma unroll
    for (int k = 1; k <= TT; ++k) {
        int jh = (rec_s[k] >> 11) & 0x1FF;
        pk[k] = PrefT[jh * NN + tid];
    }

    // c = #{j : De_j < Ue} (Ldn post-scan is non-decreasing), clamp to triangle
    int lo = 0, hi = NN;
    while (lo < hi) { int m = (lo + hi) >> 1; if (Ldn[m] < Ue) lo = m + 1; else hi = m; }
    int c = min(lo, tid + 1);
    float RT = RowTot[tid];
    float ww = 2.0f * PrefT[c * NN + tid] - RT;

    // barrier-free walk: per-thread delta per step
    float vals[TT + 2];
    vals[0] = RT; vals[1] = ww;
    int cc = c;
    #pragma unroll
    for (int k = 1; k <= TT; ++k) {
        float dl = 0.0f;
        if (k <= Tb) {
            int rec = rec_s[k];
            int d = rec & 3;
            if (d == 2) {                          // up: rows i < ih -> +RowTot
                int ih = (rec >> 2) & 0x1FF;
                if (tid < ih) { dl = RT - ww; ww = RT; cc = tid + 1; }
            } else if (d == 0) {                   // down: truncate prefix to jh
                int jh = (rec >> 11) & 0x1FF;
                if (cc > jh) { float wn = 2.0f * pk[k] - RT; dl = wn - ww; ww = wn; cc = jh; }
            }
        }
        vals[1 + k] = dl;
    }

    // reduce all TT+2 quantities: wave shuffle then cross-wave via LDS
    #pragma unroll
    for (int q = 0; q < TT + 2; ++q)
        for (int off = 32; off; off >>= 1)
            vals[q] += __shfl_down(vals[q], off, 64);
    int lane = tid & 63, wv = tid >> 6;
    if (lane == 0) {
        #pragma unroll
        for (int q = 0; q < TT + 2; ++q) red[wv * (TT + 2) + q] = vals[q];
    }
    __syncthreads();
    if (tid < TT + 2)
        tot[tid] = red[tid] + red[(TT + 2) + tid] + red[2 * (TT + 2) + tid] + red[3 * (TT + 2) + tid];
    __syncthreads();
    if (tid < TT) {                                // prefix-scan deltas -> outputs
        float x = tot[2 + tid];
        #pragma unroll
        for (int off = 1; off < TT; off <<= 1) {
            float y = __shfl_up(x, off, 64);
            if (tid >= off) x += y;
        }
        if (tid < Tb) out[t0 + tid] = (tot[1] + x) * (1.0f / tot[0]);
    }
}

extern "C" void kernel_launch(void* const* d_in, const int* in_sizes, int n_in,
                              void* d_out, int out_size, void* d_ws, size_t ws_size,
                              hipStream_t stream) {
    const float* h   = (const float*)d_in[0];
    const float* raw = (const float*)d_in[1];
    float* out = (float*)d_out;
    int M = in_sizes[0];            // 4000
    int G = (M + TT - 1) / TT;      // 250 blocks

    char* ws = (char*)d_ws;
    size_t off = 0;
    auto take = [&](size_t bytes) { size_t cur = off; off = (off + bytes + 255) & ~(size_t)255; return cur; };
    float* PrefT  = (float*)(ws + take((size_t)(NN + 1) * NN * 4));
    float* RowTot = (float*)(ws + take((size_t)NN * 4));

    kA<<<NN, 256, 0, stream>>>(raw, PrefT, RowTot);
    kB<<<G, 256, 0, stream>>>(h, PrefT, RowTot, out, M);
}